// Round 2
// baseline (2449.453 us; speedup 1.0000x reference)
//
#include <hip/hip_runtime.h>
#include <hip/hip_bf16.h>
#include <cstddef>

typedef float f32x4 __attribute__((ext_vector_type(4)));
typedef short bf16x8 __attribute__((ext_vector_type(8)));

__device__ __forceinline__ unsigned short f2bf(float f){
  union { float f; unsigned u; } v; v.f = f;
  unsigned r = v.u + 0x7fffu + ((v.u >> 16) & 1u);
  return (unsigned short)(r >> 16);
}
__device__ __forceinline__ float bf2f(unsigned short s){
  union { unsigned u; float f; } v; v.u = ((unsigned)s) << 16;
  return v.f;
}

// ---------------- fp32 -> bf16 weight conversion ----------------
__global__ void cvt_bf16(const float* __restrict__ in, unsigned short* __restrict__ out, int n){
  int i = blockIdx.x * blockDim.x + threadIdx.x;
  if (i < n) out[i] = f2bf(in[i]);
}

// ---------------- LayerNorm (wave per token). REMAP=1: gather via shift+window-partition ----
template<int REMAP>
__global__ __launch_bounds__(256) void ln_kern(const float* __restrict__ xin,
                                               const float* __restrict__ g,
                                               const float* __restrict__ bta,
                                               unsigned short* __restrict__ xout){
  int token = blockIdx.x * 4 + (threadIdx.x >> 6);
  int lane  = threadIdx.x & 63;
  size_t src;
  if (REMAP){
    int t = token % 49, win = token / 49;
    int b = win >> 6, w64 = win & 63;
    int wi = w64 >> 3, wj = w64 & 7;
    int ty = t / 7, tx = t - ty*7;
    int h = wi*7 + ty + 3; if (h >= 56) h -= 56;   // roll(-3) gather
    int w = wj*7 + tx + 3; if (w >= 56) w -= 56;
    src = ((size_t)b*3136 + h*56 + w) * 192;
  } else {
    src = (size_t)token * 192;
  }
  const float* row = xin + src;
  float v0 = row[lane], v1 = row[lane+64], v2 = row[lane+128];
  float s = v0+v1+v2, s2 = v0*v0+v1*v1+v2*v2;
  #pragma unroll
  for (int off=32; off; off>>=1){ s += __shfl_xor(s, off); s2 += __shfl_xor(s2, off); }
  float mu  = s * (1.f/192.f);
  float var = s2*(1.f/192.f) - mu*mu;
  float rs  = rsqrtf(var + 1e-6f);
  unsigned short* orow = xout + (size_t)token*192;
  orow[lane]     = f2bf((v0-mu)*rs*g[lane]     + bta[lane]);
  orow[lane+64]  = f2bf((v1-mu)*rs*g[lane+64]  + bta[lane+64]);
  orow[lane+128] = f2bf((v2-mu)*rs*g[lane+128] + bta[lane+128]);
}

// ---------------- GEMM, K=192 staged fully in LDS. C = A(Mx192) @ W(NDx192)^T + bias ------
// EPI 0: bf16 store   EPI 1: gelu -> bf16   EPI 2: window-reverse scatter + residual, f32
template<int ND, int EPI>
__global__ __launch_bounds__(256) void gemm_k192(const unsigned short* __restrict__ A,
                                                 const unsigned short* __restrict__ W,
                                                 const float* __restrict__ bias,
                                                 void* __restrict__ outp,
                                                 const float* __restrict__ resid){
  __shared__ unsigned short As[128][200];        // pad 192->200: conflict-free b128 reads
  const int tid = threadIdx.x;
  const int m0  = blockIdx.x * 128;
  {
    int row = tid >> 1, half = tid & 1;
    const unsigned short* src = A + (size_t)(m0 + row)*192 + half*96;
    unsigned short* dst = &As[row][half*96];
    #pragma unroll
    for (int i=0;i<12;i++)
      *(bf16x8*)(dst + i*8) = *(const bf16x8*)(src + i*8);
  }
  __syncthreads();
  const int wave = tid >> 6, lane = tid & 63;
  const int l15 = lane & 15, l4 = lane >> 4;
  const int mw = wave * 32;
  const unsigned short* ap0 = &As[mw + l15][l4*8];

  for (int nt = 0; nt < ND/16; nt++){
    const int n0 = nt*16;
    f32x4 acc0 = {0.f,0.f,0.f,0.f}, acc1 = {0.f,0.f,0.f,0.f};
    const unsigned short* wpp = W + (size_t)(n0 + l15)*192 + l4*8;
    #pragma unroll
    for (int kk=0;kk<6;kk++){
      bf16x8 bfr = *(const bf16x8*)(wpp + kk*32);
      bf16x8 a0  = *(const bf16x8*)(ap0 + kk*32);
      bf16x8 a1  = *(const bf16x8*)(ap0 + 16*200 + kk*32);
      acc0 = __builtin_amdgcn_mfma_f32_16x16x32_bf16(a0, bfr, acc0, 0, 0, 0);
      acc1 = __builtin_amdgcn_mfma_f32_16x16x32_bf16(a1, bfr, acc1, 0, 0, 0);
    }
    const float bn = bias[n0 + l15];
    #pragma unroll
    for (int f=0; f<2; f++){
      f32x4 acc = f ? acc1 : acc0;
      #pragma unroll
      for (int j=0;j<4;j++){
        const int m = m0 + mw + f*16 + l4*4 + j;   // D row = (lane>>4)*4 + reg (m89-verified)
        float val = acc[j] + bn;
        if (EPI == 0){
          ((unsigned short*)outp)[(size_t)m*ND + n0 + l15] = f2bf(val);
        } else if (EPI == 1){
          float gv = 0.5f*val*(1.f + erff(val*0.70710678118654752f));
          ((unsigned short*)outp)[(size_t)m*ND + n0 + l15] = f2bf(gv);
        } else {
          int t = m % 49, win = m / 49;
          int b = win >> 6, w64 = win & 63;
          int wi = w64 >> 3, wj = w64 & 7;
          int ty = t / 7, tx = t - ty*7;
          int h = wi*7 + ty + 3; if (h >= 56) h -= 56;  // roll(+3) scatter
          int w = wj*7 + tx + 3; if (w >= 56) w -= 56;
          size_t o = ((size_t)b*3136 + h*56 + w)*192 + n0 + l15;
          ((float*)outp)[o] = resid[o] + val;
        }
      }
    }
  }
}

// ---------------- fc2: K=768 chunked, ND=192, out += (residual RMW on d_out=y) ----------
__global__ __launch_bounds__(256) void gemm_fc2(const unsigned short* __restrict__ A,
                                                const unsigned short* __restrict__ W,
                                                const float* __restrict__ bias,
                                                float* __restrict__ out){
  __shared__ unsigned short As[128][200];
  const int tid = threadIdx.x;
  const int m0  = blockIdx.x * 128;
  const int wave = tid>>6, lane = tid&63;
  const int l15 = lane&15, l4 = lane>>4;
  const int mw = wave*32;
  f32x4 acc[12][2];
  #pragma unroll
  for (int nt=0;nt<12;nt++){ acc[nt][0]=(f32x4){0,0,0,0}; acc[nt][1]=(f32x4){0,0,0,0}; }
  const unsigned short* ap0 = &As[mw + l15][l4*8];
  for (int kc=0; kc<4; kc++){
    __syncthreads();
    {
      int row = tid>>1, half = tid&1;
      const unsigned short* src = A + (size_t)(m0+row)*768 + kc*192 + half*96;
      unsigned short* dst = &As[row][half*96];
      #pragma unroll
      for (int i=0;i<12;i++) *(bf16x8*)(dst+i*8) = *(const bf16x8*)(src+i*8);
    }
    __syncthreads();
    #pragma unroll
    for (int nt=0;nt<12;nt++){
      const unsigned short* wpp = W + (size_t)(nt*16 + l15)*768 + kc*192 + l4*8;
      #pragma unroll
      for (int kk=0;kk<6;kk++){
        bf16x8 bfr = *(const bf16x8*)(wpp + kk*32);
        bf16x8 a0  = *(const bf16x8*)(ap0 + kk*32);
        bf16x8 a1  = *(const bf16x8*)(ap0 + 16*200 + kk*32);
        acc[nt][0] = __builtin_amdgcn_mfma_f32_16x16x32_bf16(a0, bfr, acc[nt][0], 0,0,0);
        acc[nt][1] = __builtin_amdgcn_mfma_f32_16x16x32_bf16(a1, bfr, acc[nt][1], 0,0,0);
      }
    }
  }
  #pragma unroll
  for (int nt=0;nt<12;nt++){
    const float bn = bias[nt*16 + l15];
    #pragma unroll
    for (int f=0;f<2;f++){
      #pragma unroll
      for (int j=0;j<4;j++){
        int m = m0 + mw + f*16 + l4*4 + j;
        size_t oidx = (size_t)m*192 + nt*16 + l15;
        out[oidx] += acc[nt][f][j] + bn;
      }
    }
  }
}

// ---------------- windowed attention: block = window, wave = head, lane = query row ------
__global__ __launch_bounds__(384) void attn_kern(const unsigned short* __restrict__ qkv,
                                                 const float* __restrict__ rel_bias,
                                                 unsigned short* __restrict__ o){
  __shared__ unsigned short S[49][584];   // 49 tokens x 576 (q|k|v), padded stride
  __shared__ float BIAS[1014];            // 169 x 6
  __shared__ int REG[49];
  const int w = blockIdx.x;               // 0..4095 = b*64 + win
  const int tid = threadIdx.x;
  {
    const unsigned short* src = qkv + (size_t)w*49*576;
    for (int idx = tid; idx < 49*72; idx += 384){
      int r = idx / 72, c = (idx - r*72)*8;
      *(bf16x8*)&S[r][c] = *(const bf16x8*)&src[r*576 + c];
    }
    for (int i = tid; i < 1014; i += 384) BIAS[i] = rel_bias[i];
    if (tid < 49){
      int w64 = w & 63;
      int wi = w64 >> 3, wj = w64 & 7;
      int ty = tid / 7, tx = tid - ty*7;
      int hs = wi*7 + ty, wsp = wj*7 + tx;
      int rr = (hs < 49) ? 0 : ((hs < 53) ? 1 : 2);
      int cc = (wsp < 49) ? 0 : ((wsp < 53) ? 1 : 2);
      REG[tid] = rr*3 + cc;
    }
  }
  __syncthreads();
  const int head = tid >> 6, lane = tid & 63;
  if (lane >= 49) return;
  const int qo = head*32;
  float q[32];
  #pragma unroll
  for (int c=0;c<32;c+=8){
    bf16x8 qv = *(const bf16x8*)&S[lane][qo + c];
    #pragma unroll
    for (int i=0;i<8;i++) q[c+i] = bf2f((unsigned short)qv[i]) * 0.17677669529663689f;
  }
  const int myreg = REG[lane];
  const int yi = lane / 7, xi = lane - yi*7;
  float s[49];
  #pragma unroll
  for (int j=0;j<49;j++){
    float dot = 0.f;
    const unsigned short* kr = &S[j][192 + qo];   // uniform addr -> LDS broadcast
    #pragma unroll
    for (int c=0;c<32;c+=8){
      bf16x8 kv = *(const bf16x8*)&kr[c];
      #pragma unroll
      for (int i=0;i<8;i++) dot += q[c+i] * bf2f((unsigned short)kv[i]);
    }
    int yj = j/7, xj = j - yj*7;
    float bv = BIAS[((yi-yj+6)*13 + (xi-xj+6))*6 + head];
    float mv = (myreg != REG[j]) ? -100.f : 0.f;
    s[j] = dot + bv + mv;
  }
  float mx = -1e30f;
  #pragma unroll
  for (int j=0;j<49;j++) mx = fmaxf(mx, s[j]);
  float sum = 0.f;
  #pragma unroll
  for (int j=0;j<49;j++){ s[j] = __expf(s[j]-mx); sum += s[j]; }
  float inv = 1.f/sum;
  float acc[32];
  #pragma unroll
  for (int i=0;i<32;i++) acc[i]=0.f;
  #pragma unroll
  for (int j=0;j<49;j++){
    float p = fmaxf(s[j]*inv, 1e-8f);
    const unsigned short* vr = &S[j][384 + qo];
    #pragma unroll
    for (int c=0;c<32;c+=8){
      bf16x8 vv = *(const bf16x8*)&vr[c];
      #pragma unroll
      for (int i=0;i<8;i++) acc[c+i] += p * bf2f((unsigned short)vv[i]);
    }
  }
  unsigned short* orow = o + ((size_t)w*49 + lane)*192 + qo;
  #pragma unroll
  for (int c=0;c<32;c+=8){
    bf16x8 ov;
    #pragma unroll
    for (int i=0;i<8;i++) ov[i] = (short)f2bf(acc[c+i]);
    *(bf16x8*)&orow[c] = ov;
  }
}

extern "C" void kernel_launch(void* const* d_in, const int* in_sizes, int n_in,
                              void* d_out, int out_size, void* d_ws, size_t ws_size,
                              hipStream_t stream){
  const float* x      = (const float*)d_in[0];
  const float* qkv_w  = (const float*)d_in[1];
  const float* qkv_b  = (const float*)d_in[2];
  const float* proj_w = (const float*)d_in[3];
  const float* proj_b = (const float*)d_in[4];
  const float* rel_b  = (const float*)d_in[5];
  const float* n1g    = (const float*)d_in[6];
  const float* n1b    = (const float*)d_in[7];
  const float* n2g    = (const float*)d_in[8];
  const float* n2b    = (const float*)d_in[9];
  const float* f1w    = (const float*)d_in[10];
  const float* f1b    = (const float*)d_in[11];
  const float* f2w    = (const float*)d_in[12];
  const float* f2b    = (const float*)d_in[13];
  float* out = (float*)d_out;
  char* ws = (char*)d_ws;

  unsigned short* wq   = (unsigned short*)(ws);               // 576x192 bf16
  unsigned short* wp   = (unsigned short*)(ws + 221184);      // 192x192
  unsigned short* w1   = (unsigned short*)(ws + 294912);      // 768x192
  unsigned short* w2   = (unsigned short*)(ws + 589824);      // 192x768
  unsigned short* bufA = (unsigned short*)(ws + 1048576);     // 200704x192 bf16 (xw / attn_out / ln2)
  unsigned short* bufB = (unsigned short*)(ws + 1048576 + 77070336); // qkv (x576) then h1 (x768)

  cvt_bf16<<<432,256,0,stream>>>(qkv_w, wq, 110592);
  cvt_bf16<<<144,256,0,stream>>>(proj_w, wp, 36864);
  cvt_bf16<<<576,256,0,stream>>>(f1w, w1, 147456);
  cvt_bf16<<<576,256,0,stream>>>(f2w, w2, 147456);

  ln_kern<1><<<50176,256,0,stream>>>(x, n1g, n1b, bufA);                 // LN1 + shift + partition
  gemm_k192<576,0><<<1568,256,0,stream>>>(bufA, wq, qkv_b, bufB, nullptr); // QKV
  attn_kern<<<4096,384,0,stream>>>(bufB, rel_b, bufA);                   // attention -> bufA
  gemm_k192<192,2><<<1568,256,0,stream>>>(bufA, wp, proj_b, out, x);     // proj + reverse + residual -> y(d_out)
  ln_kern<0><<<50176,256,0,stream>>>(out, n2g, n2b, bufA);               // LN2
  gemm_k192<768,1><<<1568,256,0,stream>>>(bufA, w1, f1b, bufB, nullptr); // fc1 + gelu
  gemm_fc2<<<1568,256,0,stream>>>(bufB, w2, f2b, out);                   // fc2 + residual RMW
}

// Round 3
// 1704.775 us; speedup vs baseline: 1.4368x; 1.4368x over previous
//
#include <hip/hip_runtime.h>
#include <hip/hip_bf16.h>
#include <cstddef>

typedef float f32x4 __attribute__((ext_vector_type(4)));
typedef short bf16x8 __attribute__((ext_vector_type(8)));

__device__ __forceinline__ unsigned short f2bf(float f){
  union { float f; unsigned u; } v; v.f = f;
  unsigned r = v.u + 0x7fffu + ((v.u >> 16) & 1u);
  return (unsigned short)(r >> 16);
}
__device__ __forceinline__ float bf2f(unsigned short s){
  union { unsigned u; float f; } v; v.u = ((unsigned)s) << 16;
  return v.f;
}

// ---------------- fp32 -> bf16 weight conversion ----------------
__global__ void cvt_bf16(const float* __restrict__ in, unsigned short* __restrict__ out, int n){
  int i = blockIdx.x * blockDim.x + threadIdx.x;
  if (i < n) out[i] = f2bf(in[i]);
}

// ---------------- bias+mask table: Tb[class][head][key m][query n], bf16 ----------------
__global__ void build_tbl(const float* __restrict__ rel_bias, unsigned short* __restrict__ Tb){
  int idx = blockIdx.x*256 + threadIdx.x;
  if (idx >= 57624) return;                 // 4*6*49*49
  int n = idx % 49; int m = (idx/49) % 49; int h = (idx/2401) % 6; int c = idx/14406;
  int yn = n/7, xn = n%7, ym = m/7, xm = m%7;
  int rel = (yn - ym + 6)*13 + (xn - xm + 6);
  float b = rel_bias[rel*6 + h];
  int cr = c>>1, cc = c&1;
  int regn = (cr ? (yn<4?3:6) : 0) + (cc ? (xn<4?1:2) : 0);
  int regm = (cr ? (ym<4?3:6) : 0) + (cc ? (xm<4?1:2) : 0);
  float mk = (regn != regm) ? -100.f : 0.f;
  Tb[idx] = f2bf(b + mk);
}

// ---------------- LayerNorm (wave per token). REMAP=1: gather via shift+window-partition ----
template<int REMAP>
__global__ __launch_bounds__(256) void ln_kern(const float* __restrict__ xin,
                                               const float* __restrict__ g,
                                               const float* __restrict__ bta,
                                               unsigned short* __restrict__ xout){
  int token = blockIdx.x * 4 + (threadIdx.x >> 6);
  int lane  = threadIdx.x & 63;
  size_t src;
  if (REMAP){
    int t = token % 49, win = token / 49;
    int b = win >> 6, w64 = win & 63;
    int wi = w64 >> 3, wj = w64 & 7;
    int ty = t / 7, tx = t - ty*7;
    int h = wi*7 + ty + 3; if (h >= 56) h -= 56;   // roll(-3) gather
    int w = wj*7 + tx + 3; if (w >= 56) w -= 56;
    src = ((size_t)b*3136 + h*56 + w) * 192;
  } else {
    src = (size_t)token * 192;
  }
  const float* row = xin + src;
  float v0 = row[lane], v1 = row[lane+64], v2 = row[lane+128];
  float s = v0+v1+v2, s2 = v0*v0+v1*v1+v2*v2;
  #pragma unroll
  for (int off=32; off; off>>=1){ s += __shfl_xor(s, off); s2 += __shfl_xor(s2, off); }
  float mu  = s * (1.f/192.f);
  float var = s2*(1.f/192.f) - mu*mu;
  float rs  = rsqrtf(var + 1e-6f);
  unsigned short* orow = xout + (size_t)token*192;
  orow[lane]     = f2bf((v0-mu)*rs*g[lane]     + bta[lane]);
  orow[lane+64]  = f2bf((v1-mu)*rs*g[lane+64]  + bta[lane+64]);
  orow[lane+128] = f2bf((v2-mu)*rs*g[lane+128] + bta[lane+128]);
}

// ---------------- GEMM, K=192 staged fully in LDS. C = A(Mx192) @ W(NDx192)^T + bias ------
template<int ND, int EPI>
__global__ __launch_bounds__(256) void gemm_k192(const unsigned short* __restrict__ A,
                                                 const unsigned short* __restrict__ W,
                                                 const float* __restrict__ bias,
                                                 void* __restrict__ outp,
                                                 const float* __restrict__ resid){
  __shared__ unsigned short As[128][200];
  const int tid = threadIdx.x;
  const int m0  = blockIdx.x * 128;
  {
    int row = tid >> 1, half = tid & 1;
    const unsigned short* src = A + (size_t)(m0 + row)*192 + half*96;
    unsigned short* dst = &As[row][half*96];
    #pragma unroll
    for (int i=0;i<12;i++)
      *(bf16x8*)(dst + i*8) = *(const bf16x8*)(src + i*8);
  }
  __syncthreads();
  const int wave = tid >> 6, lane = tid & 63;
  const int l15 = lane & 15, l4 = lane >> 4;
  const int mw = wave * 32;
  const unsigned short* ap0 = &As[mw + l15][l4*8];

  for (int nt = 0; nt < ND/16; nt++){
    const int n0 = nt*16;
    f32x4 acc0 = {0.f,0.f,0.f,0.f}, acc1 = {0.f,0.f,0.f,0.f};
    const unsigned short* wpp = W + (size_t)(n0 + l15)*192 + l4*8;
    #pragma unroll
    for (int kk=0;kk<6;kk++){
      bf16x8 bfr = *(const bf16x8*)(wpp + kk*32);
      bf16x8 a0  = *(const bf16x8*)(ap0 + kk*32);
      bf16x8 a1  = *(const bf16x8*)(ap0 + 16*200 + kk*32);
      acc0 = __builtin_amdgcn_mfma_f32_16x16x32_bf16(a0, bfr, acc0, 0, 0, 0);
      acc1 = __builtin_amdgcn_mfma_f32_16x16x32_bf16(a1, bfr, acc1, 0, 0, 0);
    }
    const float bn = bias[n0 + l15];
    #pragma unroll
    for (int f=0; f<2; f++){
      f32x4 acc = f ? acc1 : acc0;
      #pragma unroll
      for (int j=0;j<4;j++){
        const int m = m0 + mw + f*16 + l4*4 + j;
        float val = acc[j] + bn;
        if (EPI == 0){
          ((unsigned short*)outp)[(size_t)m*ND + n0 + l15] = f2bf(val);
        } else if (EPI == 1){
          float gv = 0.5f*val*(1.f + erff(val*0.70710678118654752f));
          ((unsigned short*)outp)[(size_t)m*ND + n0 + l15] = f2bf(gv);
        } else {
          int t = m % 49, win = m / 49;
          int b = win >> 6, w64 = win & 63;
          int wi = w64 >> 3, wj = w64 & 7;
          int ty = t / 7, tx = t - ty*7;
          int h = wi*7 + ty + 3; if (h >= 56) h -= 56;  // roll(+3) scatter
          int w = wj*7 + tx + 3; if (w >= 56) w -= 56;
          size_t o = ((size_t)b*3136 + h*56 + w)*192 + n0 + l15;
          ((float*)outp)[o] = resid[o] + val;
        }
      }
    }
  }
}

// ---------------- fc2: K=768 chunked, ND=192, out += (residual RMW on d_out=y) ----------
__global__ __launch_bounds__(256) void gemm_fc2(const unsigned short* __restrict__ A,
                                                const unsigned short* __restrict__ W,
                                                const float* __restrict__ bias,
                                                float* __restrict__ out){
  __shared__ unsigned short As[128][200];
  const int tid = threadIdx.x;
  const int m0  = blockIdx.x * 128;
  const int wave = tid>>6, lane = tid&63;
  const int l15 = lane&15, l4 = lane>>4;
  const int mw = wave*32;
  f32x4 acc[12][2];
  #pragma unroll
  for (int nt=0;nt<12;nt++){ acc[nt][0]=(f32x4){0,0,0,0}; acc[nt][1]=(f32x4){0,0,0,0}; }
  const unsigned short* ap0 = &As[mw + l15][l4*8];
  for (int kc=0; kc<4; kc++){
    __syncthreads();
    {
      int row = tid>>1, half = tid&1;
      const unsigned short* src = A + (size_t)(m0+row)*768 + kc*192 + half*96;
      unsigned short* dst = &As[row][half*96];
      #pragma unroll
      for (int i=0;i<12;i++) *(bf16x8*)(dst+i*8) = *(const bf16x8*)(src+i*8);
    }
    __syncthreads();
    #pragma unroll
    for (int nt=0;nt<12;nt++){
      const unsigned short* wpp = W + (size_t)(nt*16 + l15)*768 + kc*192 + l4*8;
      #pragma unroll
      for (int kk=0;kk<6;kk++){
        bf16x8 bfr = *(const bf16x8*)(wpp + kk*32);
        bf16x8 a0  = *(const bf16x8*)(ap0 + kk*32);
        bf16x8 a1  = *(const bf16x8*)(ap0 + 16*200 + kk*32);
        acc[nt][0] = __builtin_amdgcn_mfma_f32_16x16x32_bf16(a0, bfr, acc[nt][0], 0,0,0);
        acc[nt][1] = __builtin_amdgcn_mfma_f32_16x16x32_bf16(a1, bfr, acc[nt][1], 0,0,0);
      }
    }
  }
  #pragma unroll
  for (int nt=0;nt<12;nt++){
    const float bn = bias[nt*16 + l15];
    #pragma unroll
    for (int f=0;f<2;f++){
      #pragma unroll
      for (int j=0;j<4;j++){
        int m = m0 + mw + f*16 + l4*4 + j;
        size_t oidx = (size_t)m*192 + nt*16 + l15;
        out[oidx] += acc[nt][f][j] + bn;
      }
    }
  }
}

// ---------------- MFMA windowed attention: block = window, wave = head ------------------
// S^T = K·Q^T (swapped so softmax keys are in-lane + 2 shfls), PV as O^T = V^T·P^T.
__global__ __launch_bounds__(384, 3) void attn_mfma(const unsigned short* __restrict__ qkv,
                                                    const unsigned short* __restrict__ Tb,
                                                    unsigned short* __restrict__ o){
  __shared__ unsigned short Vt[192*72];       // V transposed [channel][token], col-rotated by 8*(row>>3)
  __shared__ unsigned short Pt[6*16*72];      // per-wave P^T bounce: [head][query q][key]
  const int w = blockIdx.x;
  const int tid = threadIdx.x;
  const unsigned short* base = qkv + (size_t)w*28224;   // 49*576

  // stage V transposed (col rotation kills the rows-8-apart bank collision)
  for (int idx = tid; idx < 1176; idx += 384){
    int t = idx/24, cg = idx%24;
    bf16x8 vv = *(const bf16x8*)(base + t*576 + 384 + cg*8);
    int pc = (t + 8*cg) & 63;
    #pragma unroll
    for (int i=0;i<8;i++) Vt[(cg*8+i)*72 + pc] = (unsigned short)vv[i];
  }
  for (int idx = tid; idx < 192*15; idx += 384){          // zero pad tokens 49..63
    int r = idx/15, t = 49 + idx%15;
    Vt[r*72 + ((t + 8*(r>>3)) & 63)] = 0;
  }
  __syncthreads();

  const int head = tid>>6, lane = tid&63;
  const int g = lane>>4, q = lane&15;

  // K A-frags (row = key = q within tile, k = d = g*8+i) straight from global (L2-hot)
  bf16x8 ak[4];
  #pragma unroll
  for (int kt=0;kt<4;kt++){
    int krow = kt*16 + q; if (krow > 48) krow = 48;       // clamp: pad keys masked later
    ak[kt] = *(const bf16x8*)(base + krow*576 + 192 + head*32 + g*8);
  }
  // V^T A-frags from LDS
  bf16x8 av[2][2];
  #pragma unroll
  for (int mt=0;mt<2;mt++){
    int r = head*32 + mt*16 + q;                           // channel row
    #pragma unroll
    for (int kc=0;kc<2;kc++){
      int pc = (kc*32 + g*8 + 8*(r>>3)) & 63;
      av[mt][kc] = *(const bf16x8*)&Vt[r*72 + pc];
    }
  }
  const int cls = ((((w>>3)&7)==7) ? 2:0) | (((w&7)==7) ? 1:0);
  const unsigned short* tb = Tb + ((size_t)cls*6 + head)*2401;
  unsigned short* ptw = &Pt[head*1152];                    // 16*72 per wave

  f32x4 acc[2][4];
  #pragma unroll
  for (int mt=0;mt<2;mt++)
    #pragma unroll
    for (int qt=0;qt<4;qt++) acc[mt][qt] = (f32x4){0.f,0.f,0.f,0.f};

  #pragma unroll
  for (int qt=0;qt<4;qt++){
    int n = qt*16 + q;
    int qrow = n > 48 ? 48 : n;
    bf16x8 bq = *(const bf16x8*)(base + qrow*576 + head*32 + g*8);
    f32x4 z = {0.f,0.f,0.f,0.f};
    f32x4 st[4];
    #pragma unroll
    for (int kt=0;kt<4;kt++)
      st[kt] = __builtin_amdgcn_mfma_f32_16x16x32_bf16(ak[kt], bq, z, 0, 0, 0);

    // epilogue: scale + bias/mask table + pad-key mask
    float pv[4][4];
    #pragma unroll
    for (int kt=0;kt<4;kt++){
      #pragma unroll
      for (int r=0;r<4;r++){
        int m = kt*16 + g*4 + r;
        float tv = 0.f;
        if (m < 49 && n < 49) tv = bf2f(tb[m*49 + n]);
        pv[kt][r] = (m < 49) ? st[kt][r]*0.17677669529663689f + tv : -1e30f;
      }
    }
    // softmax over keys (16 in-lane + groups via xor 16/32; same query per group)
    float mx = pv[0][0];
    #pragma unroll
    for (int kt=0;kt<4;kt++)
      #pragma unroll
      for (int r=0;r<4;r++) mx = fmaxf(mx, pv[kt][r]);
    mx = fmaxf(mx, __shfl_xor(mx, 16));
    mx = fmaxf(mx, __shfl_xor(mx, 32));
    float sum = 0.f;
    #pragma unroll
    for (int kt=0;kt<4;kt++)
      #pragma unroll
      for (int r=0;r<4;r++){ float e = __expf(pv[kt][r]-mx); pv[kt][r] = e; sum += e; }
    sum += __shfl_xor(sum, 16);
    sum += __shfl_xor(sum, 32);
    float inv = 1.f/sum;
    #pragma unroll
    for (int kt=0;kt<4;kt++){
      unsigned pk[2];
      #pragma unroll
      for (int hw=0;hw<2;hw++){
        float p0 = fmaxf(pv[kt][hw*2+0]*inv, 1e-8f);
        float p1 = fmaxf(pv[kt][hw*2+1]*inv, 1e-8f);
        int m0_ = kt*16 + g*4 + hw*2;
        if (m0_   >= 49) p0 = 0.f;
        if (m0_+1 >= 49) p1 = 0.f;
        pk[hw] = (unsigned)f2bf(p0) | ((unsigned)f2bf(p1) << 16);
      }
      *(uint2*)&ptw[q*72 + kt*16 + g*4] = make_uint2(pk[0], pk[1]);
    }
    // read back as B-frags (col = query q, k = key g*8+i) and PV-MFMA
    bf16x8 bp0 = *(const bf16x8*)&ptw[q*72 + 0*32 + g*8];
    bf16x8 bp1 = *(const bf16x8*)&ptw[q*72 + 1*32 + g*8];
    #pragma unroll
    for (int mt=0;mt<2;mt++){
      acc[mt][qt] = __builtin_amdgcn_mfma_f32_16x16x32_bf16(av[mt][0], bp0, acc[mt][qt], 0,0,0);
      acc[mt][qt] = __builtin_amdgcn_mfma_f32_16x16x32_bf16(av[mt][1], bp1, acc[mt][qt], 0,0,0);
    }
  }
  // store O: row d = head*32+mt*16+g*4+r, col token n (guard n<49)
  #pragma unroll
  for (int qt=0;qt<4;qt++){
    int n = qt*16 + q;
    if (n < 49){
      #pragma unroll
      for (int mt=0;mt<2;mt++){
        unsigned lo = (unsigned)f2bf(acc[mt][qt][0]) | ((unsigned)f2bf(acc[mt][qt][1]) << 16);
        unsigned hi = (unsigned)f2bf(acc[mt][qt][2]) | ((unsigned)f2bf(acc[mt][qt][3]) << 16);
        *(uint2*)(o + ((size_t)w*49 + n)*192 + head*32 + mt*16 + g*4) = make_uint2(lo, hi);
      }
    }
  }
}

extern "C" void kernel_launch(void* const* d_in, const int* in_sizes, int n_in,
                              void* d_out, int out_size, void* d_ws, size_t ws_size,
                              hipStream_t stream){
  const float* x      = (const float*)d_in[0];
  const float* qkv_w  = (const float*)d_in[1];
  const float* qkv_b  = (const float*)d_in[2];
  const float* proj_w = (const float*)d_in[3];
  const float* proj_b = (const float*)d_in[4];
  const float* rel_b  = (const float*)d_in[5];
  const float* n1g    = (const float*)d_in[6];
  const float* n1b    = (const float*)d_in[7];
  const float* n2g    = (const float*)d_in[8];
  const float* n2b    = (const float*)d_in[9];
  const float* f1w    = (const float*)d_in[10];
  const float* f1b    = (const float*)d_in[11];
  const float* f2w    = (const float*)d_in[12];
  const float* f2b    = (const float*)d_in[13];
  float* out = (float*)d_out;
  char* ws = (char*)d_ws;

  unsigned short* wq   = (unsigned short*)(ws);               // 576x192 bf16
  unsigned short* wp   = (unsigned short*)(ws + 221184);      // 192x192
  unsigned short* w1   = (unsigned short*)(ws + 294912);      // 768x192
  unsigned short* w2   = (unsigned short*)(ws + 589824);      // 192x768
  unsigned short* tb   = (unsigned short*)(ws + 884736);      // 4*6*49*49 bf16 bias+mask table
  unsigned short* bufA = (unsigned short*)(ws + 1048576);     // 200704x192 bf16
  unsigned short* bufB = (unsigned short*)(ws + 1048576 + 77070336); // qkv (x576) then h1 (x768)

  cvt_bf16<<<432,256,0,stream>>>(qkv_w, wq, 110592);
  cvt_bf16<<<144,256,0,stream>>>(proj_w, wp, 36864);
  cvt_bf16<<<576,256,0,stream>>>(f1w, w1, 147456);
  cvt_bf16<<<576,256,0,stream>>>(f2w, w2, 147456);
  build_tbl<<<226,256,0,stream>>>(rel_b, tb);

  ln_kern<1><<<50176,256,0,stream>>>(x, n1g, n1b, bufA);                 // LN1 + shift + partition
  gemm_k192<576,0><<<1568,256,0,stream>>>(bufA, wq, qkv_b, bufB, nullptr); // QKV
  attn_mfma<<<4096,384,0,stream>>>(bufB, tb, bufA);                      // attention -> bufA
  gemm_k192<192,2><<<1568,256,0,stream>>>(bufA, wp, proj_b, out, x);     // proj + reverse + residual
  ln_kern<0><<<50176,256,0,stream>>>(out, n2g, n2b, bufA);               // LN2
  gemm_k192<768,1><<<1568,256,0,stream>>>(bufA, w1, f1b, bufB, nullptr); // fc1 + gelu
  gemm_fc2<<<1568,256,0,stream>>>(bufB, w2, f2b, out);                   // fc2 + residual RMW
}